// Round 1
// baseline (945.022 us; speedup 1.0000x reference)
//
#include <hip/hip_runtime.h>

constexpr int Bm = 8, Hm = 16, Sm = 1024, Dm = 64;
constexpr int BH = Bm * Hm;          // 128
constexpr int NBLK = BH * (Sm / 16); // 8192 blocks
constexpr int STRIDE = 1040;         // bf16 elems per strip row (pad: 520 words % 32 = 8 -> bank spread)

typedef short short8  __attribute__((ext_vector_type(8)));
typedef float floatx4 __attribute__((ext_vector_type(4)));
typedef int   intx4   __attribute__((ext_vector_type(4)));

__device__ inline unsigned short f2bf(float f) {
    unsigned u = __builtin_bit_cast(unsigned, f);
    u += 0x7fffu + ((u >> 16) & 1u);          // RNE
    return (unsigned short)(u >> 16);
}
__device__ inline float bf2f(unsigned short h) {
    unsigned u = ((unsigned)h) << 16;
    return __builtin_bit_cast(float, u);
}

// One block = one (b,h) x 16 query rows. 4 waves split the 1024 keys.
// LDS strip: 16 x 1040 bf16 (33,280 B) -> 4 blocks/CU.
//
// XCD swizzle: dispatcher round-robins consecutive blockIdx across the 8 XCDs,
// so without remap each XCD's ~128 resident blocks span ~16 bh -> 8 MB of K/V
// working set vs 4 MB L2 -> K/V re-reads (4.2 GB logical) thrash to L3/HBM.
// Remap (bid&7)*1024 + bid>>3: each XCD walks 16 bh SEQUENTIALLY; in-flight
// window ~2 bh = 1 MB K+V -> L2-resident. 8192 % 8 == 0 -> bijective.
__global__ __launch_bounds__(256, 4)
void attn_fused(const float* __restrict__ Q, const float* __restrict__ K,
                const float* __restrict__ V, const int* __restrict__ Msk,
                float* __restrict__ Out, float* __restrict__ Attn)
{
    __shared__ __align__(16) unsigned short strip[16 * STRIDE];

    const int tid  = threadIdx.x;
    const int wave = tid >> 6;
    const int lane = tid & 63;
    const int quad = lane >> 4;
    const int ln   = lane & 15;

    const int bid = (blockIdx.x & 7) * (NBLK >> 3) + (blockIdx.x >> 3);
    const int bh = bid >> 6;          // 64 consecutive logical blocks share bh
    const int qt = bid & 63;
    const int q0 = qt << 4;
    const int b  = bh >> 4;           // H = 16

    const float* Qb = Q + (size_t)bh * (Sm * Dm);
    const float* Kb = K + (size_t)bh * (Sm * Dm);
    const float* Vb = V + (size_t)bh * (Sm * Dm);

    // ---- Q fragments, 1/sqrt(64)=0.125 folded in (exact: power of 2) ----
    // A layout: A[m=lane&15][k=quad*8+j]
    short8 aq0, aq1;
    {
        const float* qrow = Qb + (q0 + ln) * Dm + quad * 8;
        floatx4 a = *(const floatx4*)(qrow);
        floatx4 c = *(const floatx4*)(qrow + 4);
        floatx4 d = *(const floatx4*)(qrow + 32);
        floatx4 e = *(const floatx4*)(qrow + 36);
        #pragma unroll
        for (int i = 0; i < 4; ++i) {
            aq0[i]     = (short)f2bf(a[i] * 0.125f);
            aq0[i + 4] = (short)f2bf(c[i] * 0.125f);
            aq1[i]     = (short)f2bf(d[i] * 0.125f);
            aq1[i + 4] = (short)f2bf(e[i] * 0.125f);
        }
    }

    // ---- Phase A: raw scores -> bf16 strip. Wave w covers keys [w*256, w*256+256). ----
    for (int kt = wave * 16; kt < wave * 16 + 16; ++kt) {
        // B layout: B[k=quad*8+j][n=lane&15] = K[key = kt*16 + n][d = quad*8+j]
        const float* krow = Kb + (kt * 16 + ln) * Dm + quad * 8;
        floatx4 k0 = *(const floatx4*)(krow);
        floatx4 k1 = *(const floatx4*)(krow + 4);
        floatx4 k2 = *(const floatx4*)(krow + 32);
        floatx4 k3 = *(const floatx4*)(krow + 36);
        short8 b0, b1;
        #pragma unroll
        for (int i = 0; i < 4; ++i) {
            b0[i]     = (short)f2bf(k0[i]);
            b0[i + 4] = (short)f2bf(k1[i]);
            b1[i]     = (short)f2bf(k2[i]);
            b1[i + 4] = (short)f2bf(k3[i]);
        }
        floatx4 c = {0.f, 0.f, 0.f, 0.f};
        c = __builtin_amdgcn_mfma_f32_16x16x32_bf16(aq0, b0, c, 0, 0, 0);
        c = __builtin_amdgcn_mfma_f32_16x16x32_bf16(aq1, b1, c, 0, 0, 0);
        // C layout: col = lane&15 (key), row = quad*4 + r (query)
        const int colb = kt * 16 + ln;
        #pragma unroll
        for (int r = 0; r < 4; ++r)
            strip[(quad * 4 + r) * STRIDE + colb] = f2bf(c[r]);
    }
    __syncthreads();

    // ---- Softmax (exact: max, exp, sum) + post-softmax mask + attn output ----
    {
        const int row = tid >> 4, l = tid & 15;   // 16 threads per row, contiguous lanes
        unsigned short* srow = strip + row * STRIDE;

        float mx = -1e30f;
        #pragma unroll
        for (int i = 0; i < 8; ++i) {
            short8 v = *(const short8*)(srow + l * 8 + i * 128);
            #pragma unroll
            for (int j = 0; j < 8; ++j) mx = fmaxf(mx, bf2f((unsigned short)v[j]));
        }
        #pragma unroll
        for (int off = 8; off >= 1; off >>= 1) mx = fmaxf(mx, __shfl_xor(mx, off, 16));

        float sum = 0.f;
        #pragma unroll
        for (int i = 0; i < 8; ++i) {
            short8 v = *(const short8*)(srow + l * 8 + i * 128);
            short8 e;
            #pragma unroll
            for (int j = 0; j < 8; ++j) {
                float x = __expf(bf2f((unsigned short)v[j]) - mx);
                sum += x;
                e[j] = (short)f2bf(x);
            }
            *(short8*)(srow + l * 8 + i * 128) = e;
        }
        #pragma unroll
        for (int off = 8; off >= 1; off >>= 1) sum += __shfl_xor(sum, off, 16);
        const float rn = 1.f / sum;

        const int* mrow  = Msk + (size_t)b * (Sm * Sm) + (size_t)(q0 + row) * Sm;
        float*     arow  = Attn + ((size_t)bh * Sm + (q0 + row)) * Sm;
        #pragma unroll
        for (int i = 0; i < 8; ++i) {
            const int c0 = l * 8 + i * 128;
            short8 v  = *(const short8*)(srow + c0);
            intx4  m0 = *(const intx4*)(mrow + c0);
            intx4  m1 = *(const intx4*)(mrow + c0 + 4);
            float p[8];
            #pragma unroll
            for (int j = 0; j < 4; ++j) {
                p[j]     = (m0[j] != 0) ? bf2f((unsigned short)v[j])     * rn : -100000.f;
                p[j + 4] = (m1[j] != 0) ? bf2f((unsigned short)v[j + 4]) * rn : -100000.f;
            }
            floatx4 o0, o1;
            short8 pf;
            #pragma unroll
            for (int j = 0; j < 4; ++j) { o0[j] = p[j]; o1[j] = p[j + 4]; }
            #pragma unroll
            for (int j = 0; j < 8; ++j) pf[j] = (short)f2bf(p[j]);
            *(short8*)(srow + c0) = pf;              // strip now holds P' (post-mask, bf16)
            *(floatx4*)(arow + c0)     = o0;         // attn output (fp32, -100000 exact)
            *(floatx4*)(arow + c0 + 4) = o1;
        }
    }
    __syncthreads();

    // ---- Phase B: O = P' @ V. Wave w covers keys [w*256, w*256+256); strip rows are A-frags. ----
    floatx4 acc[4] = {{0,0,0,0},{0,0,0,0},{0,0,0,0},{0,0,0,0}};
    for (int kb = wave * 256; kb < wave * 256 + 256; kb += 32) {
        // A[m=ln][k=quad*8+j] = P'[q=ln][key=kb+quad*8+j] -- already bf16 in LDS
        short8 af = *(const short8*)(strip + ln * STRIDE + kb + quad * 8);
        const float* vbase = Vb + (kb + quad * 8) * Dm + ln;
        #pragma unroll
        for (int n0 = 0; n0 < 4; ++n0) {
            // B[k=quad*8+j][n=ln] = V[key=kb+quad*8+j][d=n0*16+ln]
            short8 bf;
            #pragma unroll
            for (int j = 0; j < 8; ++j)
                bf[j] = (short)f2bf(vbase[j * Dm + n0 * 16]);
            acc[n0] = __builtin_amdgcn_mfma_f32_16x16x32_bf16(af, bf, acc[n0], 0, 0, 0);
        }
    }
    __syncthreads();

    // ---- Cross-wave partial reduce for O through LDS (reuses strip) ----
    float* part = (float*)strip;                 // [4][16][64] fp32 = 16 KB
    #pragma unroll
    for (int n0 = 0; n0 < 4; ++n0)
        #pragma unroll
        for (int r = 0; r < 4; ++r)
            part[wave * 1024 + (quad * 4 + r) * 64 + n0 * 16 + ln] = acc[n0][r];
    __syncthreads();
    {
        const int o4 = tid * 4;                  // 1024 outputs, 4 per thread
        floatx4 s = *(const floatx4*)(part + o4);
        s += *(const floatx4*)(part + 1024 + o4);
        s += *(const floatx4*)(part + 2048 + o4);
        s += *(const floatx4*)(part + 3072 + o4);
        const int row = o4 >> 6, dc = o4 & 63;
        *(floatx4*)(Out + (size_t)bh * (Sm * Dm) + (size_t)(q0 + row) * Dm + dc) = s;
    }
}

extern "C" void kernel_launch(void* const* d_in, const int* in_sizes, int n_in,
                              void* d_out, int out_size, void* d_ws, size_t ws_size,
                              hipStream_t stream)
{
    const float* Q   = (const float*)d_in[0];
    const float* K   = (const float*)d_in[1];
    const float* V   = (const float*)d_in[2];
    const int*   Msk = (const int*)d_in[3];
    float* Out  = (float*)d_out;
    float* Attn = Out + (size_t)Bm * Hm * Sm * Dm;   // out first, then attn (return order)

    attn_fused<<<dim3(NBLK), dim3(256), 0, stream>>>(Q, K, V, Msk, Out, Attn);
}

// Round 6
// 882.595 us; speedup vs baseline: 1.0707x; 1.0707x over previous
//
#include <hip/hip_runtime.h>

constexpr int Bm = 8, Hm = 16, Sm = 1024, Dm = 64;
constexpr int BH = Bm * Hm;          // 128
constexpr int NBLK = BH * (Sm / 16); // 8192 blocks
constexpr int STRIDE = 1040;         // bf16 elems per strip row (pad: 520 words % 32 = 8 -> bank spread)

typedef short short8  __attribute__((ext_vector_type(8)));
typedef float floatx4 __attribute__((ext_vector_type(4)));
typedef int   intx4   __attribute__((ext_vector_type(4)));

__device__ inline unsigned short f2bf(float f) {
    unsigned u = __builtin_bit_cast(unsigned, f);
    u += 0x7fffu + ((u >> 16) & 1u);          // RNE
    return (unsigned short)(u >> 16);
}
__device__ inline float bf2f(unsigned short h) {
    unsigned u = ((unsigned)h) << 16;
    return __builtin_bit_cast(float, u);
}

// ---------------------------------------------------------------------------
// Pre-pass: K fp32 -> bf16 (same [bh][key][d] layout), V fp32 -> bf16 V^T
// ([bh][d][key]).  Hoists the fp32->bf16 conversion that every one of the 64
// blocks per bh used to redo (identical RNE -> bit-identical results), and
// turns Phase B's 256 scalar V loads per wave into 32 contiguous short8 loads.
// ---------------------------------------------------------------------------
__global__ __launch_bounds__(256)
void preconv(const float* __restrict__ K, const float* __restrict__ V,
             unsigned short* __restrict__ Kbf, unsigned short* __restrict__ VT)
{
    __shared__ unsigned short tile[64][72];   // [key][d], pad to 144B rows (16B-aligned)

    const int blk = blockIdx.x;               // 128 bh * 16 key-tiles
    const int bh  = blk >> 4;
    const int t   = blk & 15;
    const int tid = threadIdx.x;
    const int row = tid >> 2;                 // 0..63
    const int c0  = (tid & 3) << 4;           // 0,16,32,48

    // K: straight convert, 16 contiguous elems per thread
    {
        const float* src = K + ((size_t)bh * Sm + t * 64 + row) * Dm + c0;
        unsigned short* dst = Kbf + ((size_t)bh * Sm + t * 64 + row) * Dm + c0;
        floatx4 a0 = *(const floatx4*)(src);
        floatx4 a1 = *(const floatx4*)(src + 4);
        floatx4 a2 = *(const floatx4*)(src + 8);
        floatx4 a3 = *(const floatx4*)(src + 12);
        short8 p0, p1;
        #pragma unroll
        for (int i = 0; i < 4; ++i) {
            p0[i]     = (short)f2bf(a0[i]);
            p0[i + 4] = (short)f2bf(a1[i]);
            p1[i]     = (short)f2bf(a2[i]);
            p1[i + 4] = (short)f2bf(a3[i]);
        }
        *(short8*)(dst)     = p0;
        *(short8*)(dst + 8) = p1;
    }

    // V: convert + 64x64 tile transpose through LDS
    {
        const float* src = V + ((size_t)bh * Sm + t * 64 + row) * Dm + c0;
        floatx4 a0 = *(const floatx4*)(src);
        floatx4 a1 = *(const floatx4*)(src + 4);
        floatx4 a2 = *(const floatx4*)(src + 8);
        floatx4 a3 = *(const floatx4*)(src + 12);
        short8 p0, p1;
        #pragma unroll
        for (int i = 0; i < 4; ++i) {
            p0[i]     = (short)f2bf(a0[i]);
            p0[i + 4] = (short)f2bf(a1[i]);
            p1[i]     = (short)f2bf(a2[i]);
            p1[i + 4] = (short)f2bf(a3[i]);
        }
        *(short8*)(&tile[row][c0])     = p0;
        *(short8*)(&tile[row][c0 + 8]) = p1;
    }
    __syncthreads();
    {
        const int drow = tid >> 2;            // 0..63 (d)
        const int kc0  = (tid & 3) << 4;      // key chunk
        unsigned short* dst = VT + ((size_t)bh * Dm + drow) * Sm + t * 64 + kc0;
        short8 p0, p1;
        #pragma unroll
        for (int j = 0; j < 8; ++j) {
            p0[j] = (short)tile[kc0 + j][drow];
            p1[j] = (short)tile[kc0 + 8 + j][drow];
        }
        *(short8*)(dst)     = p0;
        *(short8*)(dst + 8) = p1;
    }
}

// ---------------------------------------------------------------------------
// Main fused kernel, bf16 K / V^T inputs.
// One block = one (b,h) x 16 query rows. 4 waves split the 1024 keys.
// LDS strip: 16 x 1040 bf16 (33,280 B) -> 4 blocks/CU.
// XCD swizzle keeps each XCD's in-flight K/V working set L2-resident.
// ---------------------------------------------------------------------------
__global__ __launch_bounds__(256, 4)
void attn_fused(const float* __restrict__ Q, const unsigned short* __restrict__ Kbf,
                const unsigned short* __restrict__ VT, const int* __restrict__ Msk,
                float* __restrict__ Out, float* __restrict__ Attn)
{
    __shared__ __align__(16) unsigned short strip[16 * STRIDE];

    const int tid  = threadIdx.x;
    const int wave = tid >> 6;
    const int lane = tid & 63;
    const int quad = lane >> 4;
    const int ln   = lane & 15;

    const int bid = (blockIdx.x & 7) * (NBLK >> 3) + (blockIdx.x >> 3);
    const int bh = bid >> 6;
    const int qt = bid & 63;
    const int q0 = qt << 4;
    const int b  = bh >> 4;           // H = 16

    const float* Qb = Q + (size_t)bh * (Sm * Dm);
    const unsigned short* Kb = Kbf + (size_t)bh * (Sm * Dm);
    const unsigned short* Vb = VT + (size_t)bh * (Dm * Sm);

    // ---- Q fragments, 1/sqrt(64)=0.125 folded in (exact: power of 2) ----
    short8 aq0, aq1;
    {
        const float* qrow = Qb + (q0 + ln) * Dm + quad * 8;
        floatx4 a = *(const floatx4*)(qrow);
        floatx4 c = *(const floatx4*)(qrow + 4);
        floatx4 d = *(const floatx4*)(qrow + 32);
        floatx4 e = *(const floatx4*)(qrow + 36);
        #pragma unroll
        for (int i = 0; i < 4; ++i) {
            aq0[i]     = (short)f2bf(a[i] * 0.125f);
            aq0[i + 4] = (short)f2bf(c[i] * 0.125f);
            aq1[i]     = (short)f2bf(d[i] * 0.125f);
            aq1[i + 4] = (short)f2bf(e[i] * 0.125f);
        }
    }

    // ---- Phase A: raw scores -> bf16 strip. Wave w covers keys [w*256, w*256+256). ----
    for (int kt = wave * 16; kt < wave * 16 + 16; ++kt) {
        // B[k=quad*8+j][n=lane&15] = K[key = kt*16 + n][d = quad*8+j] -- bf16 direct
        const unsigned short* krow = Kb + (kt * 16 + ln) * Dm + quad * 8;
        short8 b0 = *(const short8*)(krow);
        short8 b1 = *(const short8*)(krow + 32);
        floatx4 c = {0.f, 0.f, 0.f, 0.f};
        c = __builtin_amdgcn_mfma_f32_16x16x32_bf16(aq0, b0, c, 0, 0, 0);
        c = __builtin_amdgcn_mfma_f32_16x16x32_bf16(aq1, b1, c, 0, 0, 0);
        const int colb = kt * 16 + ln;
        #pragma unroll
        for (int r = 0; r < 4; ++r)
            strip[(quad * 4 + r) * STRIDE + colb] = f2bf(c[r]);
    }
    __syncthreads();

    // ---- Softmax (exact: max, exp, sum) + post-softmax mask + attn output ----
    {
        const int row = tid >> 4, l = tid & 15;
        unsigned short* srow = strip + row * STRIDE;

        float mx = -1e30f;
        #pragma unroll
        for (int i = 0; i < 8; ++i) {
            short8 v = *(const short8*)(srow + l * 8 + i * 128);
            #pragma unroll
            for (int j = 0; j < 8; ++j) mx = fmaxf(mx, bf2f((unsigned short)v[j]));
        }
        #pragma unroll
        for (int off = 8; off >= 1; off >>= 1) mx = fmaxf(mx, __shfl_xor(mx, off, 16));

        float sum = 0.f;
        #pragma unroll
        for (int i = 0; i < 8; ++i) {
            short8 v = *(const short8*)(srow + l * 8 + i * 128);
            short8 e;
            #pragma unroll
            for (int j = 0; j < 8; ++j) {
                float x = __expf(bf2f((unsigned short)v[j]) - mx);
                sum += x;
                e[j] = (short)f2bf(x);
            }
            *(short8*)(srow + l * 8 + i * 128) = e;
        }
        #pragma unroll
        for (int off = 8; off >= 1; off >>= 1) sum += __shfl_xor(sum, off, 16);
        const float rn = 1.f / sum;

        const int* mrow  = Msk + (size_t)b * (Sm * Sm) + (size_t)(q0 + row) * Sm;
        float*     arow  = Attn + ((size_t)bh * Sm + (q0 + row)) * Sm;
        #pragma unroll
        for (int i = 0; i < 8; ++i) {
            const int c0 = l * 8 + i * 128;
            short8 v  = *(const short8*)(srow + c0);
            intx4  m0 = *(const intx4*)(mrow + c0);
            intx4  m1 = *(const intx4*)(mrow + c0 + 4);
            float p[8];
            #pragma unroll
            for (int j = 0; j < 4; ++j) {
                p[j]     = (m0[j] != 0) ? bf2f((unsigned short)v[j])     * rn : -100000.f;
                p[j + 4] = (m1[j] != 0) ? bf2f((unsigned short)v[j + 4]) * rn : -100000.f;
            }
            floatx4 o0, o1;
            short8 pf;
            #pragma unroll
            for (int j = 0; j < 4; ++j) { o0[j] = p[j]; o1[j] = p[j + 4]; }
            #pragma unroll
            for (int j = 0; j < 8; ++j) pf[j] = (short)f2bf(p[j]);
            *(short8*)(srow + c0) = pf;              // strip now holds P' (post-mask, bf16)
            *(floatx4*)(arow + c0)     = o0;
            *(floatx4*)(arow + c0 + 4) = o1;
        }
    }
    __syncthreads();

    // ---- Phase B: O = P' @ V. Wave w covers keys [w*256, w*256+256). ----
    floatx4 acc[4] = {{0,0,0,0},{0,0,0,0},{0,0,0,0},{0,0,0,0}};
    for (int kb = wave * 256; kb < wave * 256 + 256; kb += 32) {
        // A[m=ln][k=quad*8+j] = P'[q=ln][key=kb+quad*8+j]
        short8 af = *(const short8*)(strip + ln * STRIDE + kb + quad * 8);
        const unsigned short* vbase = Vb + kb + quad * 8;
        #pragma unroll
        for (int n0 = 0; n0 < 4; ++n0) {
            // B[k=quad*8+j][n=ln] = VT[d=n0*16+ln][key=kb+quad*8+j] -- contiguous short8
            short8 bf = *(const short8*)(vbase + (size_t)(n0 * 16 + ln) * Sm);
            acc[n0] = __builtin_amdgcn_mfma_f32_16x16x32_bf16(af, bf, acc[n0], 0, 0, 0);
        }
    }
    __syncthreads();

    // ---- Cross-wave partial reduce for O through LDS (reuses strip) ----
    float* part = (float*)strip;                 // [4][16][64] fp32 = 16 KB
    #pragma unroll
    for (int n0 = 0; n0 < 4; ++n0)
        #pragma unroll
        for (int r = 0; r < 4; ++r)
            part[wave * 1024 + (quad * 4 + r) * 64 + n0 * 16 + ln] = acc[n0][r];
    __syncthreads();
    {
        const int o4 = tid * 4;
        floatx4 s = *(const floatx4*)(part + o4);
        s += *(const floatx4*)(part + 1024 + o4);
        s += *(const floatx4*)(part + 2048 + o4);
        s += *(const floatx4*)(part + 3072 + o4);
        const int row = o4 >> 6, dc = o4 & 63;
        *(floatx4*)(Out + (size_t)bh * (Sm * Dm) + (size_t)(q0 + row) * Dm + dc) = s;
    }
}

// ---------------------------------------------------------------------------
// Legacy fallback (fp32 K/V direct) -- used only if workspace is too small.
// Identical to the round-1 verified kernel.
// ---------------------------------------------------------------------------
__global__ __launch_bounds__(256, 4)
void attn_fused_f32(const float* __restrict__ Q, const float* __restrict__ K,
                    const float* __restrict__ V, const int* __restrict__ Msk,
                    float* __restrict__ Out, float* __restrict__ Attn)
{
    __shared__ __align__(16) unsigned short strip[16 * STRIDE];

    const int tid  = threadIdx.x;
    const int wave = tid >> 6;
    const int lane = tid & 63;
    const int quad = lane >> 4;
    const int ln   = lane & 15;

    const int bid = (blockIdx.x & 7) * (NBLK >> 3) + (blockIdx.x >> 3);
    const int bh = bid >> 6;
    const int qt = bid & 63;
    const int q0 = qt << 4;
    const int b  = bh >> 4;

    const float* Qb = Q + (size_t)bh * (Sm * Dm);
    const float* Kb = K + (size_t)bh * (Sm * Dm);
    const float* Vb = V + (size_t)bh * (Sm * Dm);

    short8 aq0, aq1;
    {
        const float* qrow = Qb + (q0 + ln) * Dm + quad * 8;
        floatx4 a = *(const floatx4*)(qrow);
        floatx4 c = *(const floatx4*)(qrow + 4);
        floatx4 d = *(const floatx4*)(qrow + 32);
        floatx4 e = *(const floatx4*)(qrow + 36);
        #pragma unroll
        for (int i = 0; i < 4; ++i) {
            aq0[i]     = (short)f2bf(a[i] * 0.125f);
            aq0[i + 4] = (short)f2bf(c[i] * 0.125f);
            aq1[i]     = (short)f2bf(d[i] * 0.125f);
            aq1[i + 4] = (short)f2bf(e[i] * 0.125f);
        }
    }

    for (int kt = wave * 16; kt < wave * 16 + 16; ++kt) {
        const float* krow = Kb + (kt * 16 + ln) * Dm + quad * 8;
        floatx4 k0 = *(const floatx4*)(krow);
        floatx4 k1 = *(const floatx4*)(krow + 4);
        floatx4 k2 = *(const floatx4*)(krow + 32);
        floatx4 k3 = *(const floatx4*)(krow + 36);
        short8 b0, b1;
        #pragma unroll
        for (int i = 0; i < 4; ++i) {
            b0[i]     = (short)f2bf(k0[i]);
            b0[i + 4] = (short)f2bf(k1[i]);
            b1[i]     = (short)f2bf(k2[i]);
            b1[i + 4] = (short)f2bf(k3[i]);
        }
        floatx4 c = {0.f, 0.f, 0.f, 0.f};
        c = __builtin_amdgcn_mfma_f32_16x16x32_bf16(aq0, b0, c, 0, 0, 0);
        c = __builtin_amdgcn_mfma_f32_16x16x32_bf16(aq1, b1, c, 0, 0, 0);
        const int colb = kt * 16 + ln;
        #pragma unroll
        for (int r = 0; r < 4; ++r)
            strip[(quad * 4 + r) * STRIDE + colb] = f2bf(c[r]);
    }
    __syncthreads();

    {
        const int row = tid >> 4, l = tid & 15;
        unsigned short* srow = strip + row * STRIDE;

        float mx = -1e30f;
        #pragma unroll
        for (int i = 0; i < 8; ++i) {
            short8 v = *(const short8*)(srow + l * 8 + i * 128);
            #pragma unroll
            for (int j = 0; j < 8; ++j) mx = fmaxf(mx, bf2f((unsigned short)v[j]));
        }
        #pragma unroll
        for (int off = 8; off >= 1; off >>= 1) mx = fmaxf(mx, __shfl_xor(mx, off, 16));

        float sum = 0.f;
        #pragma unroll
        for (int i = 0; i < 8; ++i) {
            short8 v = *(const short8*)(srow + l * 8 + i * 128);
            short8 e;
            #pragma unroll
            for (int j = 0; j < 8; ++j) {
                float x = __expf(bf2f((unsigned short)v[j]) - mx);
                sum += x;
                e[j] = (short)f2bf(x);
            }
            *(short8*)(srow + l * 8 + i * 128) = e;
        }
        #pragma unroll
        for (int off = 8; off >= 1; off >>= 1) sum += __shfl_xor(sum, off, 16);
        const float rn = 1.f / sum;

        const int* mrow  = Msk + (size_t)b * (Sm * Sm) + (size_t)(q0 + row) * Sm;
        float*     arow  = Attn + ((size_t)bh * Sm + (q0 + row)) * Sm;
        #pragma unroll
        for (int i = 0; i < 8; ++i) {
            const int c0 = l * 8 + i * 128;
            short8 v  = *(const short8*)(srow + c0);
            intx4  m0 = *(const intx4*)(mrow + c0);
            intx4  m1 = *(const intx4*)(mrow + c0 + 4);
            float p[8];
            #pragma unroll
            for (int j = 0; j < 4; ++j) {
                p[j]     = (m0[j] != 0) ? bf2f((unsigned short)v[j])     * rn : -100000.f;
                p[j + 4] = (m1[j] != 0) ? bf2f((unsigned short)v[j + 4]) * rn : -100000.f;
            }
            floatx4 o0, o1;
            short8 pf;
            #pragma unroll
            for (int j = 0; j < 4; ++j) { o0[j] = p[j]; o1[j] = p[j + 4]; }
            #pragma unroll
            for (int j = 0; j < 8; ++j) pf[j] = (short)f2bf(p[j]);
            *(short8*)(srow + c0) = pf;
            *(floatx4*)(arow + c0)     = o0;
            *(floatx4*)(arow + c0 + 4) = o1;
        }
    }
    __syncthreads();

    floatx4 acc[4] = {{0,0,0,0},{0,0,0,0},{0,0,0,0},{0,0,0,0}};
    for (int kb = wave * 256; kb < wave * 256 + 256; kb += 32) {
        short8 af = *(const short8*)(strip + ln * STRIDE + kb + quad * 8);
        const float* vbase = Vb + (kb + quad * 8) * Dm + ln;
        #pragma unroll
        for (int n0 = 0; n0 < 4; ++n0) {
            short8 bf;
            #pragma unroll
            for (int j = 0; j < 8; ++j)
                bf[j] = (short)f2bf(vbase[j * Dm + n0 * 16]);
            acc[n0] = __builtin_amdgcn_mfma_f32_16x16x32_bf16(af, bf, acc[n0], 0, 0, 0);
        }
    }
    __syncthreads();

    float* part = (float*)strip;
    #pragma unroll
    for (int n0 = 0; n0 < 4; ++n0)
        #pragma unroll
        for (int r = 0; r < 4; ++r)
            part[wave * 1024 + (quad * 4 + r) * 64 + n0 * 16 + ln] = acc[n0][r];
    __syncthreads();
    {
        const int o4 = tid * 4;
        floatx4 s = *(const floatx4*)(part + o4);
        s += *(const floatx4*)(part + 1024 + o4);
        s += *(const floatx4*)(part + 2048 + o4);
        s += *(const floatx4*)(part + 3072 + o4);
        const int row = o4 >> 6, dc = o4 & 63;
        *(floatx4*)(Out + (size_t)bh * (Sm * Dm) + (size_t)(q0 + row) * Dm + dc) = s;
    }
}

extern "C" void kernel_launch(void* const* d_in, const int* in_sizes, int n_in,
                              void* d_out, int out_size, void* d_ws, size_t ws_size,
                              hipStream_t stream)
{
    const float* Q   = (const float*)d_in[0];
    const float* K   = (const float*)d_in[1];
    const float* V   = (const float*)d_in[2];
    const int*   Msk = (const int*)d_in[3];
    float* Out  = (float*)d_out;
    float* Attn = Out + (size_t)Bm * Hm * Sm * Dm;   // out first, then attn (return order)

    const size_t nElem = (size_t)BH * Sm * Dm;       // 8.39M
    const size_t need  = nElem * 2 * sizeof(unsigned short);  // Kbf + VT = 32 MB

    if (d_ws != nullptr && ws_size >= need) {
        unsigned short* Kbf = (unsigned short*)d_ws;
        unsigned short* VT  = Kbf + nElem;
        preconv<<<dim3(BH * 16), dim3(256), 0, stream>>>(K, V, Kbf, VT);
        attn_fused<<<dim3(NBLK), dim3(256), 0, stream>>>(Q, Kbf, VT, Msk, Out, Attn);
    } else {
        attn_fused_f32<<<dim3(NBLK), dim3(256), 0, stream>>>(Q, K, V, Msk, Out, Attn);
    }
}